// Round 1
// baseline (2263.886 us; speedup 1.0000x reference)
//
#include <hip/hip_runtime.h>
#include <hip/hip_bf16.h>

#define NA 8192
#define NP 65536
#define FD 128
#define TF 384
#define WROW 1920

// ---------------- init: q <- features, mu_ws <- 0 ----------------
__global__ __launch_bounds__(256) void k_init(const float* __restrict__ feat,
                                              float* __restrict__ q,
                                              float* __restrict__ mu_ws) {
    int idx = blockIdx.x * 256 + threadIdx.x;           // 0 .. 3145727
    if (idx < NA * FD) q[idx] = feat[idx];
    mu_ws[idx] = 0.f;
}

// ---------------- K1: x = silu(q@W1+b1)@W2+b2 ----------------
__global__ __launch_bounds__(256) void k_x(const float* __restrict__ q,
                                           const float* __restrict__ W1,
                                           const float* __restrict__ b1,
                                           const float* __restrict__ W2,
                                           const float* __restrict__ b2,
                                           float* __restrict__ x) {
    __shared__ float qs[16 * 128];
    __shared__ float hs[16 * 128];
    int t = threadIdx.x;
    int a0 = blockIdx.x * 16;
    #pragma unroll
    for (int r = 0; r < 8; ++r) {
        int idx = r * 256 + t;
        qs[idx] = q[a0 * 128 + idx];
    }
    __syncthreads();
    int f = t & 127, g = t >> 7;
    float acc[8];
    #pragma unroll
    for (int i = 0; i < 8; ++i) acc[i] = b1[f];
    for (int k = 0; k < 128; ++k) {
        float w = W1[k * 128 + f];
        #pragma unroll
        for (int i = 0; i < 8; ++i) acc[i] += qs[(g + 2 * i) * 128 + k] * w;
    }
    #pragma unroll
    for (int i = 0; i < 8; ++i) {
        float v = acc[i];
        hs[(g + 2 * i) * 128 + f] = v / (1.f + __expf(-v));   // silu
    }
    __syncthreads();
    float a2[24];
    #pragma unroll
    for (int c = 0; c < 3; ++c)
        #pragma unroll
        for (int i = 0; i < 8; ++i) a2[c * 8 + i] = b2[c * 128 + f];
    for (int k = 0; k < 128; ++k) {
        float w0 = W2[k * 384 + f];
        float w1 = W2[k * 384 + 128 + f];
        float w2 = W2[k * 384 + 256 + f];
        #pragma unroll
        for (int i = 0; i < 8; ++i) {
            float h = hs[(g + 2 * i) * 128 + k];
            a2[i]      += h * w0;
            a2[8 + i]  += h * w1;
            a2[16 + i] += h * w2;
        }
    }
    #pragma unroll
    for (int i = 0; i < 8; ++i) {
        int a = a0 + g + 2 * i;
        x[a * 384 + f]       = a2[i];
        x[a * 384 + 128 + f] = a2[8 + i];
        x[a * 384 + 256 + f] = a2[16 + i];
    }
}

// ---------------- K2: per-pair scatter (atomics) ----------------
// Reads mu_src (pre-update state), accumulates into q and mu_dst.
__global__ __launch_bounds__(256) void k_pair(const float* __restrict__ x,
                                              const float* __restrict__ mu_src,
                                              const float* __restrict__ rbfs,
                                              const float* __restrict__ fW,
                                              const float* __restrict__ fb,
                                              const float* __restrict__ cut,
                                              const float* __restrict__ dist,
                                              const float* __restrict__ vec,
                                              const int* __restrict__ idx_i,
                                              const int* __restrict__ idx_j,
                                              float* __restrict__ q,
                                              float* __restrict__ mu_dst,
                                              int bo) {
    int t = threadIdx.x;
    int lane = t & 63;
    int p = blockIdx.x * 4 + (t >> 6);
    int i = idx_i[p], j = idx_j[p];
    float c = cut[p];
    float inv_d = 1.f / dist[p];
    float d0 = vec[p * 3 + 0] * inv_d;
    float d1 = vec[p * 3 + 1] * inv_d;
    float d2 = vec[p * 3 + 2] * inv_d;
    float rb[20];
    #pragma unroll
    for (int r = 0; r < 20; ++r) rb[r] = rbfs[p * 20 + r];
    #pragma unroll
    for (int h = 0; h < 2; ++h) {
        int f = lane + h * 64;
        float wa = fb[bo + f], wb = fb[bo + 128 + f], wc = fb[bo + 256 + f];
        #pragma unroll
        for (int r = 0; r < 20; ++r) {
            const float* row = fW + r * WROW + bo;
            wa += rb[r] * row[f];
            wb += rb[r] * row[128 + f];
            wc += rb[r] * row[256 + f];
        }
        wa *= c; wb *= c; wc *= c;
        float xa = x[j * 384 + f] * wa;            // dq
        float xb = x[j * 384 + 128 + f] * wb;      // dmuR
        float xc = x[j * 384 + 256 + f] * wc;      // dmumu
        atomicAdd(&q[i * 128 + f], xa);
        float m0 = mu_src[(j * 3 + 0) * 128 + f];
        float m1 = mu_src[(j * 3 + 1) * 128 + f];
        float m2 = mu_src[(j * 3 + 2) * 128 + f];
        atomicAdd(&mu_dst[(i * 3 + 0) * 128 + f], xb * d0 + xc * m0);
        atomicAdd(&mu_dst[(i * 3 + 1) * 128 + f], xb * d1 + xc * m1);
        atomicAdd(&mu_dst[(i * 3 + 2) * 128 + f], xb * d2 + xc * m2);
    }
}

// ---------------- K3: mu@Wv -> muW, ||mu_V||, sum(mu_V*mu_W) ----------------
__global__ __launch_bounds__(256) void k_mixv(const float* __restrict__ mu,
                                              const float* __restrict__ Wv,
                                              float* __restrict__ muW,
                                              float* __restrict__ vn,
                                              float* __restrict__ s) {
    __shared__ float ms[16 * 384];
    int t = threadIdx.x;
    int a0 = blockIdx.x * 16;
    #pragma unroll
    for (int r = 0; r < 24; ++r) ms[r * 256 + t] = mu[a0 * 384 + r * 256 + t];
    __syncthreads();
    int f = t & 127, g = t >> 7;
    float nv[8], sv[8];
    #pragma unroll
    for (int i = 0; i < 8; ++i) { nv[i] = 0.f; sv[i] = 0.f; }
    for (int d = 0; d < 3; ++d) {
        float accV[8], accW[8];
        #pragma unroll
        for (int i = 0; i < 8; ++i) { accV[i] = 0.f; accW[i] = 0.f; }
        for (int k = 0; k < 128; ++k) {
            float w1 = Wv[k * 256 + f];
            float w2 = Wv[k * 256 + 128 + f];
            #pragma unroll
            for (int i = 0; i < 8; ++i) {
                float m = ms[(g + 2 * i) * 384 + d * 128 + k];
                accV[i] += m * w1;
                accW[i] += m * w2;
            }
        }
        #pragma unroll
        for (int i = 0; i < 8; ++i) {
            int a = a0 + g + 2 * i;
            muW[a * 384 + d * 128 + f] = accW[i];
            nv[i] += accV[i] * accV[i];
            sv[i] += accV[i] * accW[i];
        }
    }
    #pragma unroll
    for (int i = 0; i < 8; ++i) {
        int a = a0 + g + 2 * i;
        vn[a * 128 + f] = sqrtf(nv[i] + 1e-8f);
        s[a * 128 + f]  = sv[i];
    }
}

// ---------------- K4: gate MLP + q/mu update ----------------
__global__ __launch_bounds__(256) void k_mix2(const float* __restrict__ vn,
                                              const float* __restrict__ s,
                                              const float* __restrict__ muW,
                                              const float* __restrict__ W1,
                                              const float* __restrict__ b1,
                                              const float* __restrict__ W2,
                                              const float* __restrict__ b2,
                                              float* __restrict__ q,
                                              float* __restrict__ mu) {
    __shared__ float ctx[16 * 256];
    __shared__ float hs[16 * 128];
    int t = threadIdx.x;
    int a0 = blockIdx.x * 16;
    #pragma unroll
    for (int r = 0; r < 8; ++r) {
        int idx = r * 256 + t;
        int a = idx >> 7, f2 = idx & 127;
        ctx[a * 256 + f2]       = q[(a0 + a) * 128 + f2];
        ctx[a * 256 + 128 + f2] = vn[(a0 + a) * 128 + f2];
    }
    __syncthreads();
    int f = t & 127, g = t >> 7;
    float acc[8];
    #pragma unroll
    for (int i = 0; i < 8; ++i) acc[i] = b1[f];
    for (int k = 0; k < 256; ++k) {
        float w = W1[k * 128 + f];
        #pragma unroll
        for (int i = 0; i < 8; ++i) acc[i] += ctx[(g + 2 * i) * 256 + k] * w;
    }
    #pragma unroll
    for (int i = 0; i < 8; ++i) {
        float v = acc[i];
        hs[(g + 2 * i) * 128 + f] = v / (1.f + __expf(-v));
    }
    __syncthreads();
    float a2[24];
    #pragma unroll
    for (int c = 0; c < 3; ++c)
        #pragma unroll
        for (int i = 0; i < 8; ++i) a2[c * 8 + i] = b2[c * 128 + f];
    for (int k = 0; k < 128; ++k) {
        float w0 = W2[k * 384 + f];
        float w1 = W2[k * 384 + 128 + f];
        float w2 = W2[k * 384 + 256 + f];
        #pragma unroll
        for (int i = 0; i < 8; ++i) {
            float h = hs[(g + 2 * i) * 128 + k];
            a2[i]      += h * w0;
            a2[8 + i]  += h * w1;
            a2[16 + i] += h * w2;
        }
    }
    #pragma unroll
    for (int i = 0; i < 8; ++i) {
        int a = a0 + g + 2 * i;
        float dq   = a2[i];
        float dmu  = a2[8 + i];
        float dqmu = a2[16 + i];
        q[a * 128 + f] += dq + dqmu * s[a * 128 + f];
        #pragma unroll
        for (int d = 0; d < 3; ++d)
            mu[(a * 3 + d) * 128 + f] += dmu * muW[a * 384 + d * 128 + f];
    }
}

extern "C" void kernel_launch(void* const* d_in, const int* in_sizes, int n_in,
                              void* d_out, int out_size, void* d_ws, size_t ws_size,
                              hipStream_t stream) {
    const float* feat = (const float*)d_in[0];
    const float* dist = (const float*)d_in[1];
    const float* vec  = (const float*)d_in[2];
    const float* cut  = (const float*)d_in[3];
    const float* rbfs = (const float*)d_in[4];
    const float* fW   = (const float*)d_in[5];
    const float* fb   = (const float*)d_in[6];
    const float* iW1  = (const float*)d_in[7];
    const float* ib1  = (const float*)d_in[8];
    const float* iW2  = (const float*)d_in[9];
    const float* ib2  = (const float*)d_in[10];
    const float* mWv  = (const float*)d_in[11];
    const float* mW1  = (const float*)d_in[12];
    const float* mb1  = (const float*)d_in[13];
    const float* mW2  = (const float*)d_in[14];
    const float* mb2  = (const float*)d_in[15];
    const int* idx_i  = (const int*)d_in[16];
    const int* idx_j  = (const int*)d_in[17];

    float* q      = (float*)d_out;                 // 8192*128
    float* mu_out = (float*)d_out + NA * FD;       // 8192*3*128

    float* ws     = (float*)d_ws;
    float* mu_ws  = ws;                            // 3145728
    float* xbuf   = ws + 3145728;                  // 3145728
    float* muW    = ws + 2 * 3145728;              // 3145728
    float* vn     = ws + 3 * 3145728;              // 1048576
    float* sbuf   = ws + 3 * 3145728 + 1048576;    // 1048576

    k_init<<<NA * 3 * FD / 256, 256, 0, stream>>>(feat, q, mu_ws);

    for (int b = 0; b < 5; ++b) {
        float* mu_src = (b & 1) ? mu_out : mu_ws;
        float* mu_dst = (b & 1) ? mu_ws : mu_out;
        hipMemcpyAsync(mu_dst, mu_src, (size_t)NA * 3 * FD * sizeof(float),
                       hipMemcpyDeviceToDevice, stream);
        k_x<<<NA / 16, 256, 0, stream>>>(q, iW1 + b * 16384, ib1 + b * 128,
                                         iW2 + b * 49152, ib2 + b * 384, xbuf);
        k_pair<<<NP / 4, 256, 0, stream>>>(xbuf, mu_src, rbfs, fW, fb, cut, dist,
                                           vec, idx_i, idx_j, q, mu_dst, b * 384);
        k_mixv<<<NA / 16, 256, 0, stream>>>(mu_dst, mWv + b * 32768, muW, vn, sbuf);
        k_mix2<<<NA / 16, 256, 0, stream>>>(vn, sbuf, muW, mW1 + b * 32768,
                                            mb1 + b * 128, mW2 + b * 49152,
                                            mb2 + b * 384, q, mu_dst);
    }
}

// Round 2
// 890.137 us; speedup vs baseline: 2.5433x; 2.5433x over previous
//
#include <hip/hip_runtime.h>
#include <hip/hip_bf16.h>

#define NA 8192
#define NP 65536
#define FD 128
#define TF 384
#define WROW 1920

// ---------------- init: q <- features, mu_ws <- 0, counts/cursor <- 0 ----------------
__global__ __launch_bounds__(256) void k_init(const float* __restrict__ feat,
                                              float* __restrict__ q,
                                              float* __restrict__ mu_ws,
                                              int* __restrict__ counts,
                                              int* __restrict__ cursor) {
    int idx = blockIdx.x * 256 + threadIdx.x;           // 0 .. 3145727
    if (idx < NA * FD) q[idx] = feat[idx];
    mu_ws[idx] = 0.f;
    if (idx < NA) { counts[idx] = 0; cursor[idx] = 0; }
}

// ---------------- CSR build ----------------
__global__ __launch_bounds__(256) void k_hist(const int* __restrict__ idx_i,
                                              int* __restrict__ counts) {
    int p = blockIdx.x * 256 + threadIdx.x;
    if (p < NP) atomicAdd(&counts[idx_i[p]], 1);
}

__global__ __launch_bounds__(1024) void k_scan(const int* __restrict__ counts,
                                               int* __restrict__ offs) {
    __shared__ int sums[1024];
    int t = threadIdx.x;
    int local[8];
    int s = 0;
    #pragma unroll
    for (int k = 0; k < 8; ++k) { local[k] = s; s += counts[t * 8 + k]; }
    sums[t] = s;
    __syncthreads();
    for (int off = 1; off < 1024; off <<= 1) {
        int v = sums[t];
        int u = (t >= off) ? sums[t - off] : 0;
        __syncthreads();
        sums[t] = v + u;
        __syncthreads();
    }
    int base = (t > 0) ? sums[t - 1] : 0;
    #pragma unroll
    for (int k = 0; k < 8; ++k) offs[t * 8 + k] = base + local[k];
    if (t == 1023) offs[NA] = sums[1023];
}

__global__ __launch_bounds__(256) void k_fill(const int* __restrict__ idx_i,
                                              const int* __restrict__ offs,
                                              int* __restrict__ cursor,
                                              int* __restrict__ plist) {
    int p = blockIdx.x * 256 + threadIdx.x;
    if (p < NP) {
        int i = idx_i[p];
        int pos = atomicAdd(&cursor[i], 1);
        plist[offs[i] + pos] = p;
    }
}

// ---------------- K1: x = silu(q@W1+b1)@W2+b2 ----------------
__global__ __launch_bounds__(256) void k_x(const float* __restrict__ q,
                                           const float* __restrict__ W1,
                                           const float* __restrict__ b1,
                                           const float* __restrict__ W2,
                                           const float* __restrict__ b2,
                                           float* __restrict__ x) {
    __shared__ float qs[16 * 128];
    __shared__ float hs[16 * 128];
    int t = threadIdx.x;
    int a0 = blockIdx.x * 16;
    #pragma unroll
    for (int r = 0; r < 8; ++r) {
        int idx = r * 256 + t;
        qs[idx] = q[a0 * 128 + idx];
    }
    __syncthreads();
    int f = t & 127, g = t >> 7;
    float acc[8];
    #pragma unroll
    for (int i = 0; i < 8; ++i) acc[i] = b1[f];
    for (int k = 0; k < 128; ++k) {
        float w = W1[k * 128 + f];
        #pragma unroll
        for (int i = 0; i < 8; ++i) acc[i] += qs[(g + 2 * i) * 128 + k] * w;
    }
    #pragma unroll
    for (int i = 0; i < 8; ++i) {
        float v = acc[i];
        hs[(g + 2 * i) * 128 + f] = v / (1.f + __expf(-v));   // silu
    }
    __syncthreads();
    float a2[24];
    #pragma unroll
    for (int c = 0; c < 3; ++c)
        #pragma unroll
        for (int i = 0; i < 8; ++i) a2[c * 8 + i] = b2[c * 128 + f];
    for (int k = 0; k < 128; ++k) {
        float w0 = W2[k * 384 + f];
        float w1 = W2[k * 384 + 128 + f];
        float w2 = W2[k * 384 + 256 + f];
        #pragma unroll
        for (int i = 0; i < 8; ++i) {
            float h = hs[(g + 2 * i) * 128 + k];
            a2[i]      += h * w0;
            a2[8 + i]  += h * w1;
            a2[16 + i] += h * w2;
        }
    }
    #pragma unroll
    for (int i = 0; i < 8; ++i) {
        int a = a0 + g + 2 * i;
        x[a * 384 + f]       = a2[i];
        x[a * 384 + 128 + f] = a2[8 + i];
        x[a * 384 + 256 + f] = a2[16 + i];
    }
}

// ---------------- K2: per-atom gather (no atomics) ----------------
// For atom i: q[i] += sum_p dq; mu_dst[i] = mu_src[i] + sum_p dmu.
__global__ __launch_bounds__(128) void k_gather(const float* __restrict__ x,
                                                const float* __restrict__ mu_src,
                                                const float* __restrict__ rbfs,
                                                const float* __restrict__ fW,
                                                const float* __restrict__ fb,
                                                const float* __restrict__ cut,
                                                const float* __restrict__ dist,
                                                const float* __restrict__ vec,
                                                const int* __restrict__ idx_j,
                                                const int* __restrict__ offs,
                                                const int* __restrict__ plist,
                                                float* __restrict__ q,
                                                float* __restrict__ mu_dst,
                                                int bo) {
    int i = blockIdx.x;
    int f = threadIdx.x;      // 0..127
    int start = offs[i], end = offs[i + 1];
    float qa = 0.f, m0a = 0.f, m1a = 0.f, m2a = 0.f;
    float ba = fb[bo + f], bb = fb[bo + 128 + f], bc = fb[bo + 256 + f];
    for (int e = start; e < end; ++e) {
        int p = plist[e];
        int j = idx_j[p];
        float c = cut[p];
        float inv_d = 1.f / dist[p];
        float d0 = vec[p * 3 + 0] * inv_d;
        float d1 = vec[p * 3 + 1] * inv_d;
        float d2 = vec[p * 3 + 2] * inv_d;
        float wa = ba, wb = bb, wc = bc;
        #pragma unroll
        for (int r = 0; r < 20; ++r) {
            float rb = rbfs[p * 20 + r];
            const float* row = fW + r * WROW + bo;
            wa += rb * row[f];
            wb += rb * row[128 + f];
            wc += rb * row[256 + f];
        }
        wa *= c; wb *= c; wc *= c;
        qa += x[j * 384 + f] * wa;               // dq
        float xb = x[j * 384 + 128 + f] * wb;    // dmuR
        float xc = x[j * 384 + 256 + f] * wc;    // dmumu
        m0a += xb * d0 + xc * mu_src[(j * 3 + 0) * 128 + f];
        m1a += xb * d1 + xc * mu_src[(j * 3 + 1) * 128 + f];
        m2a += xb * d2 + xc * mu_src[(j * 3 + 2) * 128 + f];
    }
    q[i * 128 + f] += qa;
    mu_dst[(i * 3 + 0) * 128 + f] = mu_src[(i * 3 + 0) * 128 + f] + m0a;
    mu_dst[(i * 3 + 1) * 128 + f] = mu_src[(i * 3 + 1) * 128 + f] + m1a;
    mu_dst[(i * 3 + 2) * 128 + f] = mu_src[(i * 3 + 2) * 128 + f] + m2a;
}

// ---------------- K3: mu@Wv -> muW, ||mu_V||, sum(mu_V*mu_W) ----------------
__global__ __launch_bounds__(256) void k_mixv(const float* __restrict__ mu,
                                              const float* __restrict__ Wv,
                                              float* __restrict__ muW,
                                              float* __restrict__ vn,
                                              float* __restrict__ s) {
    __shared__ float ms[16 * 384];
    int t = threadIdx.x;
    int a0 = blockIdx.x * 16;
    #pragma unroll
    for (int r = 0; r < 24; ++r) ms[r * 256 + t] = mu[a0 * 384 + r * 256 + t];
    __syncthreads();
    int f = t & 127, g = t >> 7;
    float nv[8], sv[8];
    #pragma unroll
    for (int i = 0; i < 8; ++i) { nv[i] = 0.f; sv[i] = 0.f; }
    for (int d = 0; d < 3; ++d) {
        float accV[8], accW[8];
        #pragma unroll
        for (int i = 0; i < 8; ++i) { accV[i] = 0.f; accW[i] = 0.f; }
        for (int k = 0; k < 128; ++k) {
            float w1 = Wv[k * 256 + f];
            float w2 = Wv[k * 256 + 128 + f];
            #pragma unroll
            for (int i = 0; i < 8; ++i) {
                float m = ms[(g + 2 * i) * 384 + d * 128 + k];
                accV[i] += m * w1;
                accW[i] += m * w2;
            }
        }
        #pragma unroll
        for (int i = 0; i < 8; ++i) {
            int a = a0 + g + 2 * i;
            muW[a * 384 + d * 128 + f] = accW[i];
            nv[i] += accV[i] * accV[i];
            sv[i] += accV[i] * accW[i];
        }
    }
    #pragma unroll
    for (int i = 0; i < 8; ++i) {
        int a = a0 + g + 2 * i;
        vn[a * 128 + f] = sqrtf(nv[i] + 1e-8f);
        s[a * 128 + f]  = sv[i];
    }
}

// ---------------- K4: gate MLP + q/mu update ----------------
__global__ __launch_bounds__(256) void k_mix2(const float* __restrict__ vn,
                                              const float* __restrict__ s,
                                              const float* __restrict__ muW,
                                              const float* __restrict__ W1,
                                              const float* __restrict__ b1,
                                              const float* __restrict__ W2,
                                              const float* __restrict__ b2,
                                              float* __restrict__ q,
                                              float* __restrict__ mu) {
    __shared__ float ctx[16 * 256];
    __shared__ float hs[16 * 128];
    int t = threadIdx.x;
    int a0 = blockIdx.x * 16;
    #pragma unroll
    for (int r = 0; r < 8; ++r) {
        int idx = r * 256 + t;
        int a = idx >> 7, f2 = idx & 127;
        ctx[a * 256 + f2]       = q[(a0 + a) * 128 + f2];
        ctx[a * 256 + 128 + f2] = vn[(a0 + a) * 128 + f2];
    }
    __syncthreads();
    int f = t & 127, g = t >> 7;
    float acc[8];
    #pragma unroll
    for (int i = 0; i < 8; ++i) acc[i] = b1[f];
    for (int k = 0; k < 256; ++k) {
        float w = W1[k * 128 + f];
        #pragma unroll
        for (int i = 0; i < 8; ++i) acc[i] += ctx[(g + 2 * i) * 256 + k] * w;
    }
    #pragma unroll
    for (int i = 0; i < 8; ++i) {
        float v = acc[i];
        hs[(g + 2 * i) * 128 + f] = v / (1.f + __expf(-v));
    }
    __syncthreads();
    float a2[24];
    #pragma unroll
    for (int c = 0; c < 3; ++c)
        #pragma unroll
        for (int i = 0; i < 8; ++i) a2[c * 8 + i] = b2[c * 128 + f];
    for (int k = 0; k < 128; ++k) {
        float w0 = W2[k * 384 + f];
        float w1 = W2[k * 384 + 128 + f];
        float w2 = W2[k * 384 + 256 + f];
        #pragma unroll
        for (int i = 0; i < 8; ++i) {
            float h = hs[(g + 2 * i) * 128 + k];
            a2[i]      += h * w0;
            a2[8 + i]  += h * w1;
            a2[16 + i] += h * w2;
        }
    }
    #pragma unroll
    for (int i = 0; i < 8; ++i) {
        int a = a0 + g + 2 * i;
        float dq   = a2[i];
        float dmu  = a2[8 + i];
        float dqmu = a2[16 + i];
        q[a * 128 + f] += dq + dqmu * s[a * 128 + f];
        #pragma unroll
        for (int d = 0; d < 3; ++d)
            mu[(a * 3 + d) * 128 + f] += dmu * muW[a * 384 + d * 128 + f];
    }
}

extern "C" void kernel_launch(void* const* d_in, const int* in_sizes, int n_in,
                              void* d_out, int out_size, void* d_ws, size_t ws_size,
                              hipStream_t stream) {
    const float* feat = (const float*)d_in[0];
    const float* dist = (const float*)d_in[1];
    const float* vec  = (const float*)d_in[2];
    const float* cut  = (const float*)d_in[3];
    const float* rbfs = (const float*)d_in[4];
    const float* fW   = (const float*)d_in[5];
    const float* fb   = (const float*)d_in[6];
    const float* iW1  = (const float*)d_in[7];
    const float* ib1  = (const float*)d_in[8];
    const float* iW2  = (const float*)d_in[9];
    const float* ib2  = (const float*)d_in[10];
    const float* mWv  = (const float*)d_in[11];
    const float* mW1  = (const float*)d_in[12];
    const float* mb1  = (const float*)d_in[13];
    const float* mW2  = (const float*)d_in[14];
    const float* mb2  = (const float*)d_in[15];
    const int* idx_i  = (const int*)d_in[16];
    const int* idx_j  = (const int*)d_in[17];

    float* q      = (float*)d_out;                 // 8192*128
    float* mu_out = (float*)d_out + NA * FD;       // 8192*3*128

    float* ws     = (float*)d_ws;
    float* mu_ws  = ws;                            // 3145728
    float* xbuf   = ws + 3145728;                  // 3145728 (aliased: muW after k_gather)
    float* muW    = xbuf;                          // alias — xbuf dead once k_gather done
    float* vn     = ws + 2 * 3145728;              // 1048576
    float* sbuf   = ws + 2 * 3145728 + 1048576;    // 1048576
    int*   counts = (int*)(ws + 2 * 3145728 + 2 * 1048576);
    int*   cursor = counts + NA;
    int*   offs   = cursor + NA;                   // NA+1 entries
    int*   plist  = offs + NA + 1;                 // NP entries

    k_init<<<NA * 3 * FD / 256, 256, 0, stream>>>(feat, q, mu_ws, counts, cursor);
    k_hist<<<NP / 256, 256, 0, stream>>>(idx_i, counts);
    k_scan<<<1, 1024, 0, stream>>>(counts, offs);
    k_fill<<<NP / 256, 256, 0, stream>>>(idx_i, offs, cursor, plist);

    for (int b = 0; b < 5; ++b) {
        float* mu_src = (b & 1) ? mu_out : mu_ws;
        float* mu_dst = (b & 1) ? mu_ws : mu_out;
        k_x<<<NA / 16, 256, 0, stream>>>(q, iW1 + b * 16384, ib1 + b * 128,
                                         iW2 + b * 49152, ib2 + b * 384, xbuf);
        k_gather<<<NA, 128, 0, stream>>>(xbuf, mu_src, rbfs, fW, fb, cut, dist,
                                         vec, idx_j, offs, plist, q, mu_dst, b * 384);
        k_mixv<<<NA / 16, 256, 0, stream>>>(mu_dst, mWv + b * 32768, muW, vn, sbuf);
        k_mix2<<<NA / 16, 256, 0, stream>>>(vn, sbuf, muW, mW1 + b * 32768,
                                            mb1 + b * 128, mW2 + b * 49152,
                                            mb2 + b * 384, q, mu_dst);
    }
}

// Round 3
// 599.234 us; speedup vs baseline: 3.7780x; 1.4855x over previous
//
#include <hip/hip_runtime.h>
#include <hip/hip_bf16.h>

#define NA 8192
#define NP 65536
#define WROW 1920

typedef short short8 __attribute__((ext_vector_type(8)));
typedef float floatx4 __attribute__((ext_vector_type(4)));

static __device__ __forceinline__ short f2bf(float f) {
    union { float f; unsigned u; } v; v.f = f;
    unsigned r = v.u + 0x7FFF + ((v.u >> 16) & 1);
    return (short)(r >> 16);
}
static __device__ __forceinline__ float bf2f(short s) {
    union { unsigned u; float f; } v;
    v.u = ((unsigned)(unsigned short)s) << 16;
    return v.f;
}
static __device__ __forceinline__ float silu(float v) {
    return v / (1.f + __expf(-v));
}

// ---------------- weight transpose + bf16 convert: Wt[b][n][k] = W[b][k][n] ----------------
__global__ __launch_bounds__(256) void k_tconv(const float* __restrict__ W,
                                               short* __restrict__ Wt,
                                               int K, int N, int total) {
    int idx = blockIdx.x * 256 + threadIdx.x;
    if (idx >= total) return;
    int kn = K * N;
    int b = idx / kn;
    int rem = idx - b * kn;
    int k = rem / N;
    int n = rem - k * N;
    Wt[b * kn + n * K + k] = f2bf(W[idx]);
}

// ---------------- init ----------------
__global__ __launch_bounds__(256) void k_init(const float* __restrict__ feat,
                                              float* __restrict__ q,
                                              float* __restrict__ mu,
                                              short* __restrict__ q_bf,
                                              short* __restrict__ mu_bfA,
                                              int* __restrict__ counts,
                                              int* __restrict__ cursor) {
    int idx = blockIdx.x * 256 + threadIdx.x;     // 0 .. NA*384-1
    if (idx < NA * 128) { float v = feat[idx]; q[idx] = v; q_bf[idx] = f2bf(v); }
    mu[idx] = 0.f;
    mu_bfA[idx] = 0;
    if (idx < NA) { counts[idx] = 0; cursor[idx] = 0; }
}

// ---------------- CSR build ----------------
__global__ __launch_bounds__(256) void k_hist(const int* __restrict__ idx_i,
                                              int* __restrict__ counts) {
    int p = blockIdx.x * 256 + threadIdx.x;
    if (p < NP) atomicAdd(&counts[idx_i[p]], 1);
}

__global__ __launch_bounds__(1024) void k_scan(const int* __restrict__ counts,
                                               int* __restrict__ offs) {
    __shared__ int sums[1024];
    int t = threadIdx.x;
    int local[8];
    int s = 0;
    #pragma unroll
    for (int k = 0; k < 8; ++k) { local[k] = s; s += counts[t * 8 + k]; }
    sums[t] = s;
    __syncthreads();
    for (int off = 1; off < 1024; off <<= 1) {
        int v = sums[t];
        int u = (t >= off) ? sums[t - off] : 0;
        __syncthreads();
        sums[t] = v + u;
        __syncthreads();
    }
    int base = (t > 0) ? sums[t - 1] : 0;
    #pragma unroll
    for (int k = 0; k < 8; ++k) offs[t * 8 + k] = base + local[k];
    if (t == 1023) offs[NA] = sums[1023];
}

__global__ __launch_bounds__(256) void k_fill(const int* __restrict__ idx_i,
                                              const int* __restrict__ offs,
                                              int* __restrict__ cursor,
                                              int* __restrict__ plist) {
    int p = blockIdx.x * 256 + threadIdx.x;
    if (p < NP) {
        int i = idx_i[p];
        int pos = atomicAdd(&cursor[i], 1);
        plist[offs[i] + pos] = p;
    }
}

// ---------------- K1 (MFMA): x = silu(q@W1+b1)@W2+b2, bf16 out ----------------
// block = 16 atoms, 4 waves. Stage1 N=128 (wave: 32 cols), stage2 N=384 (wave: 96 cols).
__global__ __launch_bounds__(256) void k_x(const short* __restrict__ q_bf,
                                           const short* __restrict__ W1t,  // [128][128]
                                           const short* __restrict__ W2t,  // [384][128]
                                           const float* __restrict__ b1,
                                           const float* __restrict__ b2,
                                           short* __restrict__ x_bf) {
    __shared__ __align__(16) short hs[16 * 128];
    int t = threadIdx.x;
    int wv = t >> 6, lane = t & 63, quad = lane >> 4, l16 = lane & 15;
    int a0 = blockIdx.x * 16;

    floatx4 acc0 = {0.f, 0.f, 0.f, 0.f}, acc1 = {0.f, 0.f, 0.f, 0.f};
    #pragma unroll
    for (int kk = 0; kk < 4; ++kk) {
        short8 a  = *(const short8*)(q_bf + (a0 + l16) * 128 + kk * 32 + quad * 8);
        short8 b0 = *(const short8*)(W1t + (wv * 32 + l16) * 128 + kk * 32 + quad * 8);
        short8 bq = *(const short8*)(W1t + (wv * 32 + 16 + l16) * 128 + kk * 32 + quad * 8);
        acc0 = __builtin_amdgcn_mfma_f32_16x16x32_bf16(a, b0, acc0, 0, 0, 0);
        acc1 = __builtin_amdgcn_mfma_f32_16x16x32_bf16(a, bq, acc1, 0, 0, 0);
    }
    {
        int n0 = wv * 32 + l16;
        float bia0 = b1[n0], bia1 = b1[n0 + 16];
        #pragma unroll
        for (int r = 0; r < 4; ++r) {
            int m = quad * 4 + r;
            hs[m * 128 + n0]      = f2bf(silu(acc0[r] + bia0));
            hs[m * 128 + n0 + 16] = f2bf(silu(acc1[r] + bia1));
        }
    }
    __syncthreads();
    floatx4 acc[6];
    #pragma unroll
    for (int jj = 0; jj < 6; ++jj) acc[jj] = {0.f, 0.f, 0.f, 0.f};
    #pragma unroll
    for (int kk = 0; kk < 4; ++kk) {
        short8 a = *(const short8*)(hs + l16 * 128 + kk * 32 + quad * 8);
        #pragma unroll
        for (int jj = 0; jj < 6; ++jj) {
            short8 b = *(const short8*)(W2t + (wv * 96 + jj * 16 + l16) * 128 + kk * 32 + quad * 8);
            acc[jj] = __builtin_amdgcn_mfma_f32_16x16x32_bf16(a, b, acc[jj], 0, 0, 0);
        }
    }
    #pragma unroll
    for (int jj = 0; jj < 6; ++jj) {
        int n = wv * 96 + jj * 16 + l16;
        float bia = b2[n];
        #pragma unroll
        for (int r = 0; r < 4; ++r) {
            int m = quad * 4 + r;
            x_bf[(a0 + m) * 384 + n] = f2bf(acc[jj][r] + bia);
        }
    }
}

// ---------------- K2: per-atom gather (bf16 sources, f32 masters in-place) ----------------
__global__ __launch_bounds__(128) void k_gather(const short* __restrict__ x_bf,
                                                const short* __restrict__ mu_bfA,
                                                const float* __restrict__ rbfs,
                                                const float* __restrict__ fW,
                                                const float* __restrict__ fb,
                                                const float* __restrict__ cut,
                                                const float* __restrict__ dist,
                                                const float* __restrict__ vec,
                                                const int* __restrict__ idx_j,
                                                const int* __restrict__ offs,
                                                const int* __restrict__ plist,
                                                float* __restrict__ q,
                                                float* __restrict__ mu,
                                                short* __restrict__ q_bf,
                                                short* __restrict__ mu_bfB,
                                                int bo) {
    int i = blockIdx.x;
    int f = threadIdx.x;      // 0..127
    // hoist pair-invariant filter weight columns into registers
    float wra[20], wrb[20], wrc[20];
    #pragma unroll
    for (int r = 0; r < 20; ++r) {
        const float* row = fW + r * WROW + bo;
        wra[r] = row[f]; wrb[r] = row[128 + f]; wrc[r] = row[256 + f];
    }
    float ba = fb[bo + f], bb = fb[bo + 128 + f], bc = fb[bo + 256 + f];
    int start = offs[i], end = offs[i + 1];
    float qa = 0.f, m0a = 0.f, m1a = 0.f, m2a = 0.f;
    for (int e = start; e < end; ++e) {
        int p = plist[e];
        int j = idx_j[p];
        float c = cut[p];
        float inv_d = 1.f / dist[p];
        float d0 = vec[p * 3 + 0] * inv_d;
        float d1 = vec[p * 3 + 1] * inv_d;
        float d2 = vec[p * 3 + 2] * inv_d;
        float wa = ba, wb = bb, wc = bc;
        #pragma unroll
        for (int r = 0; r < 20; ++r) {
            float rb = rbfs[p * 20 + r];
            wa += rb * wra[r];
            wb += rb * wrb[r];
            wc += rb * wrc[r];
        }
        wa *= c; wb *= c; wc *= c;
        qa += bf2f(x_bf[j * 384 + f]) * wa;
        float xb = bf2f(x_bf[j * 384 + 128 + f]) * wb;
        float xc = bf2f(x_bf[j * 384 + 256 + f]) * wc;
        m0a += xb * d0 + xc * bf2f(mu_bfA[(j * 3 + 0) * 128 + f]);
        m1a += xb * d1 + xc * bf2f(mu_bfA[(j * 3 + 1) * 128 + f]);
        m2a += xb * d2 + xc * bf2f(mu_bfA[(j * 3 + 2) * 128 + f]);
    }
    float qn = q[i * 128 + f] + qa;
    q[i * 128 + f] = qn;
    q_bf[i * 128 + f] = f2bf(qn);
    float mn0 = mu[(i * 3 + 0) * 128 + f] + m0a;
    float mn1 = mu[(i * 3 + 1) * 128 + f] + m1a;
    float mn2 = mu[(i * 3 + 2) * 128 + f] + m2a;
    mu[(i * 3 + 0) * 128 + f] = mn0;
    mu[(i * 3 + 1) * 128 + f] = mn1;
    mu[(i * 3 + 2) * 128 + f] = mn2;
    mu_bfB[(i * 3 + 0) * 128 + f] = f2bf(mn0);
    mu_bfB[(i * 3 + 1) * 128 + f] = f2bf(mn1);
    mu_bfB[(i * 3 + 2) * 128 + f] = f2bf(mn2);
}

// ---------------- K3 (MFMA): [muV|muW] = mu @ Wv; vn, s, muW out (bf16) ----------------
// block = 16 atoms = 48 M-rows (3 m-tiles), N=256: wave w covers cols w*64..w*64+63.
__global__ __launch_bounds__(256) void k_mixv(const short* __restrict__ mu_bfB,
                                              const short* __restrict__ Wvt,   // [256][128]
                                              short* __restrict__ muW_bf,
                                              short* __restrict__ vn_bf,
                                              short* __restrict__ s_bf) {
    __shared__ float V[48 * 260];
    int t = threadIdx.x;
    int wv = t >> 6, lane = t & 63, quad = lane >> 4, l16 = lane & 15;
    int a0 = blockIdx.x * 16;

    floatx4 acc[3][4];
    #pragma unroll
    for (int mt = 0; mt < 3; ++mt)
        #pragma unroll
        for (int nt = 0; nt < 4; ++nt) acc[mt][nt] = {0.f, 0.f, 0.f, 0.f};

    #pragma unroll
    for (int kk = 0; kk < 4; ++kk) {
        short8 a[3];
        #pragma unroll
        for (int mt = 0; mt < 3; ++mt)
            a[mt] = *(const short8*)(mu_bfB + (a0 * 3 + mt * 16 + l16) * 128 + kk * 32 + quad * 8);
        #pragma unroll
        for (int nt = 0; nt < 4; ++nt) {
            short8 b = *(const short8*)(Wvt + (wv * 64 + nt * 16 + l16) * 128 + kk * 32 + quad * 8);
            #pragma unroll
            for (int mt = 0; mt < 3; ++mt)
                acc[mt][nt] = __builtin_amdgcn_mfma_f32_16x16x32_bf16(a[mt], b, acc[mt][nt], 0, 0, 0);
        }
    }
    #pragma unroll
    for (int mt = 0; mt < 3; ++mt)
        #pragma unroll
        for (int nt = 0; nt < 4; ++nt)
            #pragma unroll
            for (int r = 0; r < 4; ++r)
                V[(mt * 16 + quad * 4 + r) * 260 + wv * 64 + nt * 16 + l16] = acc[mt][nt][r];
    __syncthreads();
    #pragma unroll
    for (int k = 0; k < 8; ++k) {
        int idx = k * 256 + t;
        int a = idx >> 7, c = idx & 127;
        float v0 = V[(a * 3 + 0) * 260 + c];
        float v1 = V[(a * 3 + 1) * 260 + c];
        float v2 = V[(a * 3 + 2) * 260 + c];
        float w0 = V[(a * 3 + 0) * 260 + 128 + c];
        float w1 = V[(a * 3 + 1) * 260 + 128 + c];
        float w2 = V[(a * 3 + 2) * 260 + 128 + c];
        float vn = sqrtf(v0 * v0 + v1 * v1 + v2 * v2 + 1e-8f);
        float sv = v0 * w0 + v1 * w1 + v2 * w2;
        int ga = a0 + a;
        vn_bf[ga * 128 + c] = f2bf(vn);
        s_bf[ga * 128 + c]  = f2bf(sv);
        muW_bf[(ga * 3 + 0) * 128 + c] = f2bf(w0);
        muW_bf[(ga * 3 + 1) * 128 + c] = f2bf(w1);
        muW_bf[(ga * 3 + 2) * 128 + c] = f2bf(w2);
    }
}

// ---------------- K4 (MFMA): gate MLP + q/mu update + mirrors ----------------
__global__ __launch_bounds__(256) void k_mix2(const short* __restrict__ q_bf_ro,
                                              const short* __restrict__ vn_bf,
                                              const short* __restrict__ s_bf,
                                              const short* __restrict__ muW_bf,
                                              const short* __restrict__ W1t,   // [128][256]
                                              const short* __restrict__ W2t,   // [384][128]
                                              const float* __restrict__ b1,
                                              const float* __restrict__ b2,
                                              float* __restrict__ q,
                                              float* __restrict__ mu,
                                              short* __restrict__ q_bf,
                                              short* __restrict__ mu_bfA) {
    __shared__ __align__(16) short hs[16 * 128];
    __shared__ float yl[16 * 388];
    int t = threadIdx.x;
    int wv = t >> 6, lane = t & 63, quad = lane >> 4, l16 = lane & 15;
    int a0 = blockIdx.x * 16;

    floatx4 acc0 = {0.f, 0.f, 0.f, 0.f}, acc1 = {0.f, 0.f, 0.f, 0.f};
    #pragma unroll
    for (int kk = 0; kk < 8; ++kk) {
        const short* src = (kk < 4)
            ? q_bf_ro + (a0 + l16) * 128 + kk * 32 + quad * 8
            : vn_bf + (a0 + l16) * 128 + (kk - 4) * 32 + quad * 8;
        short8 a  = *(const short8*)src;
        short8 b0 = *(const short8*)(W1t + (wv * 32 + l16) * 256 + kk * 32 + quad * 8);
        short8 bq = *(const short8*)(W1t + (wv * 32 + 16 + l16) * 256 + kk * 32 + quad * 8);
        acc0 = __builtin_amdgcn_mfma_f32_16x16x32_bf16(a, b0, acc0, 0, 0, 0);
        acc1 = __builtin_amdgcn_mfma_f32_16x16x32_bf16(a, bq, acc1, 0, 0, 0);
    }
    {
        int n0 = wv * 32 + l16;
        float bia0 = b1[n0], bia1 = b1[n0 + 16];
        #pragma unroll
        for (int r = 0; r < 4; ++r) {
            int m = quad * 4 + r;
            hs[m * 128 + n0]      = f2bf(silu(acc0[r] + bia0));
            hs[m * 128 + n0 + 16] = f2bf(silu(acc1[r] + bia1));
        }
    }
    __syncthreads();
    floatx4 acc[6];
    #pragma unroll
    for (int jj = 0; jj < 6; ++jj) acc[jj] = {0.f, 0.f, 0.f, 0.f};
    #pragma unroll
    for (int kk = 0; kk < 4; ++kk) {
        short8 a = *(const short8*)(hs + l16 * 128 + kk * 32 + quad * 8);
        #pragma unroll
        for (int jj = 0; jj < 6; ++jj) {
            short8 b = *(const short8*)(W2t + (wv * 96 + jj * 16 + l16) * 128 + kk * 32 + quad * 8);
            acc[jj] = __builtin_amdgcn_mfma_f32_16x16x32_bf16(a, b, acc[jj], 0, 0, 0);
        }
    }
    #pragma unroll
    for (int jj = 0; jj < 6; ++jj) {
        int n = wv * 96 + jj * 16 + l16;
        float bia = b2[n];
        #pragma unroll
        for (int r = 0; r < 4; ++r) {
            int m = quad * 4 + r;
            yl[m * 388 + n] = acc[jj][r] + bia;
        }
    }
    __syncthreads();
    #pragma unroll
    for (int k = 0; k < 8; ++k) {
        int idx = k * 256 + t;
        int a = idx >> 7, c = idx & 127;
        int ga = a0 + a;
        float dq   = yl[a * 388 + c];
        float dmu  = yl[a * 388 + 128 + c];
        float dqmu = yl[a * 388 + 256 + c];
        float sv = bf2f(s_bf[ga * 128 + c]);
        float qn = q[ga * 128 + c] + dq + dqmu * sv;
        q[ga * 128 + c] = qn;
        q_bf[ga * 128 + c] = f2bf(qn);
        #pragma unroll
        for (int d = 0; d < 3; ++d) {
            float mw = bf2f(muW_bf[(ga * 3 + d) * 128 + c]);
            float mn = mu[(ga * 3 + d) * 128 + c] + dmu * mw;
            mu[(ga * 3 + d) * 128 + c] = mn;
            mu_bfA[(ga * 3 + d) * 128 + c] = f2bf(mn);
        }
    }
}

extern "C" void kernel_launch(void* const* d_in, const int* in_sizes, int n_in,
                              void* d_out, int out_size, void* d_ws, size_t ws_size,
                              hipStream_t stream) {
    const float* feat = (const float*)d_in[0];
    const float* dist = (const float*)d_in[1];
    const float* vec  = (const float*)d_in[2];
    const float* cut  = (const float*)d_in[3];
    const float* rbfs = (const float*)d_in[4];
    const float* fW   = (const float*)d_in[5];
    const float* fb   = (const float*)d_in[6];
    const float* iW1  = (const float*)d_in[7];
    const float* ib1  = (const float*)d_in[8];
    const float* iW2  = (const float*)d_in[9];
    const float* ib2  = (const float*)d_in[10];
    const float* mWv  = (const float*)d_in[11];
    const float* mW1  = (const float*)d_in[12];
    const float* mb1  = (const float*)d_in[13];
    const float* mW2  = (const float*)d_in[14];
    const float* mb2  = (const float*)d_in[15];
    const int* idx_i  = (const int*)d_in[16];
    const int* idx_j  = (const int*)d_in[17];

    float* q  = (float*)d_out;                 // 8192*128
    float* mu = (float*)d_out + NA * 128;      // 8192*3*128 (in-place across blocks)

    char* w = (char*)d_ws;
    short* x_bf   = (short*)(w);               // 6,291,456 B
    short* q_bf   = (short*)(w + 6291456);     // 2,097,152
    short* mu_bfA = (short*)(w + 8388608);     // 6,291,456 (pre-block mu, gather src)
    short* mu_bfB = (short*)(w + 14680064);    // 6,291,456 (post-gather mu, mixv src)
    short* vn_bf  = (short*)(w + 20971520);    // 2,097,152
    short* muW_bf = (short*)(w + 23068672);    // 6,291,456
    short* s_bf   = (short*)(w + 29360128);    // 2,097,152
    short* W1t    = (short*)(w + 31457280);    // 163,840   5x[128][128]
    short* W2t    = (short*)(w + 31621120);    // 491,520   5x[384][128]
    short* Wvt    = (short*)(w + 32112640);    // 327,680   5x[256][128]
    short* mW1t   = (short*)(w + 32440320);    // 327,680   5x[128][256]
    short* mW2t   = (short*)(w + 32768000);    // 491,520   5x[384][128]
    int* counts   = (int*)(w + 33259520);
    int* cursor   = (int*)(w + 33292288);
    int* offs     = (int*)(w + 33325056);      // NA+1
    int* plist    = (int*)(w + 33357840);      // NP

    // one-time per launch: weight convert+transpose, init, CSR
    k_tconv<<<(5 * 16384 + 255) / 256, 256, 0, stream>>>(iW1, W1t, 128, 128, 5 * 16384);
    k_tconv<<<(5 * 49152 + 255) / 256, 256, 0, stream>>>(iW2, W2t, 128, 384, 5 * 49152);
    k_tconv<<<(5 * 32768 + 255) / 256, 256, 0, stream>>>(mWv, Wvt, 128, 256, 5 * 32768);
    k_tconv<<<(5 * 32768 + 255) / 256, 256, 0, stream>>>(mW1, mW1t, 256, 128, 5 * 32768);
    k_tconv<<<(5 * 49152 + 255) / 256, 256, 0, stream>>>(mW2, mW2t, 128, 384, 5 * 49152);
    k_init<<<NA * 384 / 256, 256, 0, stream>>>(feat, q, mu, q_bf, mu_bfA, counts, cursor);
    k_hist<<<NP / 256, 256, 0, stream>>>(idx_i, counts);
    k_scan<<<1, 1024, 0, stream>>>(counts, offs);
    k_fill<<<NP / 256, 256, 0, stream>>>(idx_i, offs, cursor, plist);

    for (int b = 0; b < 5; ++b) {
        k_x<<<NA / 16, 256, 0, stream>>>(q_bf, W1t + b * 16384, W2t + b * 49152,
                                         ib1 + b * 128, ib2 + b * 384, x_bf);
        k_gather<<<NA, 128, 0, stream>>>(x_bf, mu_bfA, rbfs, fW, fb, cut, dist, vec,
                                         idx_j, offs, plist, q, mu, q_bf, mu_bfB,
                                         b * 384);
        k_mixv<<<NA / 16, 256, 0, stream>>>(mu_bfB, Wvt + b * 32768, muW_bf, vn_bf, s_bf);
        k_mix2<<<NA / 16, 256, 0, stream>>>(q_bf, vn_bf, s_bf, muW_bf,
                                            mW1t + b * 32768, mW2t + b * 49152,
                                            mb1 + b * 128, mb2 + b * 384,
                                            q, mu, q_bf, mu_bfA);
    }
}